// Round 1
// baseline (3310.087 us; speedup 1.0000x reference)
//
#include <hip/hip_runtime.h>
#include <hip/hip_bf16.h>

// LSNN adaptive-LIF scan, T=1000, B=64, N_in=256, N_h=512, fp32.
//
// BITWISE CONSTRAINT (rounds 2-5): harness compares binary spikes exactly;
// flips cascade. numpy/OpenBLAS reduces k sequentially ascending, so the
// recurrent term for column n MUST be one serial ascending-index __fadd_rn
// chain over active neurons. No partial sums. Rounds 2/5 (passed, absmax 0)
// prove: sparse ascending chain + pad-with-+0.0 rows == BLAS bitwise.
//
// Round 8: diagnosed remaining bottleneck = per-tile latency serialization in
// the gather. Old structure paid (lgkm ~120cy for in-tile offset reads +
// L2 ~225cy) per 16-element tile with only the 64cy add chain hidden ->
// ~20 cy/element, 5800 cy/step. New structure: 3-stage software pipeline,
// TS=24, with DECOUPLED offset/data fetch:
//   stage(t): issue data loads for tile t+2 (offsets read 2 stages ago),
//             issue ds_read offsets for tile t+4, then chain tile t.
// Data issue->consume = 2 stages (~280cy) >= L2 latency; offsets get >=2
// stages >= lgkm latency. Offset prefetch for tiles 0/1 hoisted above the
// elementwise update so the once-per-step lgkm stall overlaps VALU work.
// Registers: 3x24 f32 bufs + 3x6 int4 offs ~ +144 VGPR -- free (grid=64 WGs
// -> 1 WG/CU, only need <=256 VGPR for 2 waves/SIMD). vmcnt at each chain
// consume = 48+eps < 63 so counted waits stay encodable.

#define TT   1000
#define BB   64
#define NIN  256
#define NH   512
#define TS   24                          // gather tile size (mult of 4)
#define LPAD (6 * TS)                    // list pad region (deep prefetch)
#define PADOFF (NH * 2048)               // byte offset of zeroed row 512 of wT

__device__ constexpr float KV = (float)(0.001 * 100.0);            // DT*TAU_MEM_INV
__device__ constexpr float KI = (float)(0.001 * 200.0);            // DT*TAU_SYN_INV
__device__ constexpr float KB = (float)(0.001 * (1.0 / 800.0));    // DT*TAU_ADAPT_INV
__device__ constexpr float KJ = (float)((1.0 / 800.0) * 1.8);      // TAU_ADAPT_INV*BETA

// ---------------- transpose w_rec (512x512): wT[j][n] = w_rec[n][j] ----------
__global__ void transp512(const float* __restrict__ in, float* __restrict__ ot) {
    __shared__ float tile[32][33];
    const int tx = threadIdx.x;            // 0..31
    const int ty = threadIdx.y;            // 0..7
    const int jcol = blockIdx.x * 32 + tx;
    const int row0 = blockIdx.y * 32;
    for (int r = ty; r < 32; r += 8)
        tile[r][tx] = in[(size_t)(row0 + r) * NH + jcol];
    __syncthreads();
    const int ncol = blockIdx.y * 32 + tx;
    const int jrow0 = blockIdx.x * 32;
    for (int r = ty; r < 32; r += 8)
        ot[(size_t)(jrow0 + r) * NH + ncol] = tile[tx][r];
}

// zero row 512 of wT (padding target for unconditional gather tiles)
__global__ void zrow(float* __restrict__ wT) {
    wT[(size_t)NH * NH + threadIdx.x] = 0.0f;
}

// ---------------- fp32 GEMM: F[m][n] = sum_k X[m][k] * W[n][k] ---------------
// UNCHANGED from round 2 (bitwise-verified against the np reference).
__global__ __launch_bounds__(256)
void gemm_ff(const float* __restrict__ X, const float* __restrict__ W,
             float* __restrict__ F, int M) {
    const int bx = blockIdx.x;   // n-tile: 0..3
    const int by = blockIdx.y;   // m-tile
    const int tid = threadIdx.x;

    __shared__ float As[32][128];
    __shared__ float Bs[32][128];

    const int tn0 = (tid & 15) * 8;
    const int tm0 = (tid >> 4) * 8;
    float acc[8][8] = {};

    const int am = tid >> 1;
    const int aq = (tid & 1) * 4;

    const float* Xb = X + (size_t)(by * 128 + am) * NIN;
    const float* Wb = W + (size_t)(bx * 128 + am) * NIN;

    for (int k0 = 0; k0 < NIN; k0 += 32) {
        __syncthreads();
#pragma unroll
        for (int i2 = 0; i2 < 4; ++i2) {
            const int q = aq + i2;
            float4 xa = *reinterpret_cast<const float4*>(Xb + k0 + q * 4);
            As[q * 4 + 0][am] = xa.x; As[q * 4 + 1][am] = xa.y;
            As[q * 4 + 2][am] = xa.z; As[q * 4 + 3][am] = xa.w;
            float4 wa = *reinterpret_cast<const float4*>(Wb + k0 + q * 4);
            Bs[q * 4 + 0][am] = wa.x; Bs[q * 4 + 1][am] = wa.y;
            Bs[q * 4 + 2][am] = wa.z; Bs[q * 4 + 3][am] = wa.w;
        }
        __syncthreads();
#pragma unroll 8
        for (int kk = 0; kk < 32; ++kk) {
            float4 a0 = *reinterpret_cast<const float4*>(&As[kk][tm0]);
            float4 a1 = *reinterpret_cast<const float4*>(&As[kk][tm0 + 4]);
            float4 b0 = *reinterpret_cast<const float4*>(&Bs[kk][tn0]);
            float4 b1 = *reinterpret_cast<const float4*>(&Bs[kk][tn0 + 4]);
            const float av[8] = {a0.x, a0.y, a0.z, a0.w, a1.x, a1.y, a1.z, a1.w};
            const float bv[8] = {b0.x, b0.y, b0.z, b0.w, b1.x, b1.y, b1.z, b1.w};
#pragma unroll
            for (int i = 0; i < 8; ++i)
#pragma unroll
                for (int j = 0; j < 8; ++j)
                    acc[i][j] += av[i] * bv[j];
        }
    }

    float* Fo = F + (size_t)(by * 128 + tm0) * NH + bx * 128 + tn0;
#pragma unroll
    for (int i = 0; i < 8; ++i) {
        *reinterpret_cast<float4*>(Fo + (size_t)i * NH) =
            make_float4(acc[i][0], acc[i][1], acc[i][2], acc[i][3]);
        *reinterpret_cast<float4*>(Fo + (size_t)i * NH + 4) =
            make_float4(acc[i][4], acc[i][5], acc[i][6], acc[i][7]);
    }
}

// ---------------- gather pipeline helpers ------------------------------------
// Offsets (block-uniform) read from LDS as int4 (ds_read_b128), data loads use
// uniform SGPR base + (row byte offset + column byte offset). sched_barrier(0)
// at call sites pins each issue group ahead of the consuming chain.
__device__ __forceinline__ void fill_offs(int4 (&o)[TS / 4], const int* lp,
                                          int base) {
#pragma unroll
    for (int i = 0; i < TS / 4; ++i)
        o[i] = *reinterpret_cast<const int4*>(lp + base + 4 * i);
}

__device__ __forceinline__ void fill_data(float (&buf)[TS], const int4 (&o)[TS / 4],
                                          const char* wb, unsigned n4) {
#pragma unroll
    for (int i = 0; i < TS / 4; ++i) {
        buf[4 * i + 0] = *reinterpret_cast<const float*>(wb + (unsigned)(o[i].x + (int)n4));
        buf[4 * i + 1] = *reinterpret_cast<const float*>(wb + (unsigned)(o[i].y + (int)n4));
        buf[4 * i + 2] = *reinterpret_cast<const float*>(wb + (unsigned)(o[i].z + (int)n4));
        buf[4 * i + 3] = *reinterpret_cast<const float*>(wb + (unsigned)(o[i].w + (int)n4));
    }
}

__device__ __forceinline__ void add_tile(const float (&buf)[TS], float& rec) {
#pragma unroll
    for (int i = 0; i < TS; ++i) rec = __fadd_rn(rec, buf[i]);
}

// ---------------- scan kernel: one WG (512 thr) per batch element -----------
// st layout: [z | v | i | b], each BB*NH floats.
__global__ __launch_bounds__(512, 1)
void lsnn_scan(const float* __restrict__ F, const float* __restrict__ wT,
               const float* __restrict__ z0, const float* __restrict__ v0,
               const float* __restrict__ i0, const float* __restrict__ b0,
               float* __restrict__ out, float* __restrict__ st,
               int t0, int Tc, int first, int last) {
    const int n    = threadIdx.x;        // neuron / column 0..511
    const int b    = blockIdx.x;         // batch
    const int lane = n & 63;
    const int wv   = n >> 6;             // wave 0..7
    const size_t bn = (size_t)b * NH + n;

    __shared__ __align__(16) int lists[2][NH + LPAD];  // row byte offsets + pad
    __shared__ int cnts[2][8];

    float v, cur, bb, zprev;
    if (first) {
        zprev = z0[bn]; v = v0[bn]; cur = i0[bn]; bb = b0[bn];
    } else {
        zprev = st[0 * BB * NH + bn];
        v     = st[1 * BB * NH + bn];
        cur   = st[2 * BB * NH + bn];
        bb    = st[3 * BB * NH + bn];
    }

    // ---- initial list build (buffer 0), ascending neuron order -------------
    int cnt;
    {
        const unsigned long long m = __ballot(zprev > 0.0f);
        if (lane == 0) cnts[0][wv] = __popcll(m);
        __syncthreads();
        int base = 0, tot = 0;
        for (int q = 0; q < 8; ++q) {
            const int c = cnts[0][q];
            if (q < wv) base += c;
            tot += c;
        }
        if (zprev > 0.0f)
            lists[0][base + __popcll(m & ((1ull << lane) - 1ull))] = n << 11;
        if (n < LPAD) lists[0][tot + n] = PADOFF;   // pad region
        __syncthreads();
        cnt = tot;
    }
    int par = 0;

    const char*  wb = reinterpret_cast<const char*>(wT);   // uniform base (SGPR)
    const unsigned n4 = (unsigned)n * 4u;                  // column byte offset
    const float* Fp = F + (size_t)b * NH + n;
    float* op = out + ((size_t)t0 * BB + b) * NH + n;

    for (int t = 0; t < Tc; ++t) {
        const int* lp = lists[par];
        float bA[TS], bB[TS], bC[TS];
        int4  oA[TS / 4], oB[TS / 4], oC[TS / 4];

        // ---- t.0: offset prefetch for tiles 0/1 (lgkm latency overlaps the
        //           elementwise update below) --------------------------------
        fill_offs(oA, lp, 0);
        fill_offs(oB, lp, TS);
        __builtin_amdgcn_sched_barrier(0);

        // ---- t.1: prefetch F, elementwise update, ballot --------------------
        const float fval = Fp[(size_t)t * BB * NH];   // consumed after gather
        const float v_dec = __fadd_rn(v, __fmul_rn(KV, __fadd_rn(__fsub_rn(0.0f, v), cur)));
        const float i_dec = __fsub_rn(cur, __fmul_rn(KI, cur));
        const float b_dec = __fadd_rn(bb, __fmul_rn(KB, __fsub_rn(1.0f, bb)));
        const float zn = (__fsub_rn(v_dec, b_dec) > 0.0f) ? 1.0f : 0.0f;
        v  = (zn > 0.0f) ? 0.0f : v_dec;
        bb = __fadd_rn(b_dec, __fmul_rn(zn, KJ));
        op[0] = zn;
        op += (size_t)BB * NH;
        const unsigned long long mm = __ballot(zn > 0.0f);
        if (lane == 0) cnts[par ^ 1][wv] = __popcll(mm);

        // ---- t.2: 3-stage pipelined serial gather over lists[par] ----------
        // One ascending __fadd_rn chain per column (bitwise == BLAS).
        // stage(t): issue data(t+2) [offs read 2 stages ago], issue offs(t+4),
        //           then chain tile t. Data hide = 2 stages >= L2 latency.
        float rec = 0.0f;
        if (cnt > 0) {
            fill_data(bA, oA, wb, n4);            // data(0): waits oA lgkm (overlapped)
            __builtin_amdgcn_sched_barrier(0);
            fill_offs(oC, lp, 2 * TS);            // offs(2)
            __builtin_amdgcn_sched_barrier(0);
            fill_data(bB, oB, wb, n4);            // data(1)
            __builtin_amdgcn_sched_barrier(0);
            fill_offs(oA, lp, 3 * TS);            // offs(3)
            __builtin_amdgcn_sched_barrier(0);
            int kt = 0;
            for (;;) {
                fill_data(bC, oC, wb, n4);        // data(t+2)
                __builtin_amdgcn_sched_barrier(0);
                fill_offs(oB, lp, kt + 4 * TS);   // offs(t+4)
                __builtin_amdgcn_sched_barrier(0);
                add_tile(bA, rec);                // tile t
                kt += TS; if (kt >= cnt) break;
                fill_data(bA, oA, wb, n4);
                __builtin_amdgcn_sched_barrier(0);
                fill_offs(oC, lp, kt + 4 * TS);
                __builtin_amdgcn_sched_barrier(0);
                add_tile(bB, rec);
                kt += TS; if (kt >= cnt) break;
                fill_data(bB, oB, wb, n4);
                __builtin_amdgcn_sched_barrier(0);
                fill_offs(oA, lp, kt + 4 * TS);
                __builtin_amdgcn_sched_barrier(0);
                add_tile(bC, rec);
                kt += TS; if (kt >= cnt) break;
            }
        }
        cur = __fadd_rn(__fadd_rn(i_dec, fval), rec);
        zprev = zn;

        __syncthreads();   // B1: cnts[par^1] published; lists[par] drained

        // ---- t.3: build next list (lists[par^1]) ----------------------------
        int base = 0, tot = 0;
        for (int q = 0; q < 8; ++q) {
            const int c = cnts[par ^ 1][q];
            if (q < wv) base += c;
            tot += c;
        }
        if (zn > 0.0f)
            lists[par ^ 1][base + __popcll(mm & ((1ull << lane) - 1ull))] = n << 11;
        if (n < LPAD) lists[par ^ 1][tot + n] = PADOFF;
        __syncthreads();   // B2: lists[par^1] ready

        par ^= 1;
        cnt = tot;
    }

    st[0 * BB * NH + bn] = zprev;
    st[1 * BB * NH + bn] = v;
    st[2 * BB * NH + bn] = cur;
    st[3 * BB * NH + bn] = bb;
    if (last) {
        float* tail = out + (size_t)TT * BB * NH;
        tail[0 * BB * NH + bn] = zprev;  // zT
        tail[1 * BB * NH + bn] = v;      // vT
        tail[2 * BB * NH + bn] = cur;    // iT
        tail[3 * BB * NH + bn] = bb;     // bT
    }
}

// ---------------------------------------------------------------------------
extern "C" void kernel_launch(void* const* d_in, const int* in_sizes, int n_in,
                              void* d_out, int out_size, void* d_ws, size_t ws_size,
                              hipStream_t stream) {
    const float* X     = (const float*)d_in[0];
    const float* z0    = (const float*)d_in[1];
    const float* v0    = (const float*)d_in[2];
    const float* i0    = (const float*)d_in[3];
    const float* b0    = (const float*)d_in[4];
    const float* w_in  = (const float*)d_in[5];
    const float* w_rec = (const float*)d_in[6];
    float* out = (float*)d_out;

    char* ws = (char*)d_ws;
    float* wT = (float*)ws;                                    // 1 MB + zero row
    const size_t wT_bytes = ((size_t)NH * NH + NH) * 4 + 2048;
    float* st = (float*)(ws + wT_bytes);                       // 512 KB
    char*  fbase = ws + wT_bytes + (512u << 10);

    const long long per = (long long)BB * NH * 4;              // bytes/step of F
    long long avail = (long long)ws_size - (long long)(wT_bytes + (512u << 10));
    int Tc;
    if (avail >= 2 * per * TT) {
        Tc = TT;
    } else {
        Tc = (int)(avail / (2 * per));
        if (Tc > TT) Tc = TT;
        Tc &= ~1;
        if (Tc < 2) Tc = 2;
    }
    const size_t fbytes = (size_t)Tc * per;
    float* Fb[2] = { (float*)fbase, (float*)(fbase + fbytes) };

    transp512<<<dim3(16, 16), dim3(32, 8), 0, stream>>>(w_rec, wT);
    zrow<<<1, NH, 0, stream>>>(wT);

    int t0 = 0, buf = 0;
    bool firstc = true;
    while (t0 < TT) {
        const int Tcur = (Tc < TT - t0) ? Tc : (TT - t0);
        const int Mc = Tcur * BB;
        gemm_ff<<<dim3(4, Mc / 128), 256, 0, stream>>>(
            X + (size_t)t0 * BB * NIN, w_in, Fb[buf], Mc);
        lsnn_scan<<<dim3(BB), dim3(512), 0, stream>>>(
            Fb[buf], wT, z0, v0, i0, b0, out, st,
            t0, Tcur, firstc ? 1 : 0, (t0 + Tcur >= TT) ? 1 : 0);
        firstc = false;
        buf ^= 1;
        t0 += Tcur;
    }
}

// Round 2
// 2793.055 us; speedup vs baseline: 1.1851x; 1.1851x over previous
//
#include <hip/hip_runtime.h>
#include <hip/hip_bf16.h>

// LSNN adaptive-LIF scan, T=1000, B=64, N_in=256, N_h=512, fp32.
//
// BITWISE CONSTRAINT (rounds 2-5): harness compares binary spikes exactly;
// flips cascade. numpy/OpenBLAS reduces k sequentially ascending, so the
// recurrent term for column n MUST be one serial ascending-index __fadd_rn
// chain over active neurons. No partial sums. Rounds 2/5 (passed, absmax 0)
// prove: sparse ascending chain + pad-with-+0.0 rows == BLAS bitwise.
//
// Round 9: round 8 (3-deep pipeline, TS=24, 2 SB/stage) REGRESSED 2422->3000us.
// Suspected toxin: ~48 outstanding vmem loads/wave x 8 waves exceeded CU
// MSHR capacity -> issue backpressure; plus extra sched_barriers serialized
// the add chain against the offset ds_reads. This round reverts to the
// round-7 shape (TS=16, 2 data buffers, <=32+4 loads in flight/wave) and
// isolates ONE lever: offsets pre-read into registers one tile ahead, so
// data loads never wait lgkm in-tile (round 7 paid ~120cy lgkm per tile
// inside fill_tile). One sched_barrier per tile (after data-load group
// only) so next tile's ds_reads interleave into the add chain. Offsets for
// tiles 0/1 hoisted above the elementwise update (lgkm hides under VALU).

#define TT   1000
#define BB   64
#define NIN  256
#define NH   512
#define TS   16                          // gather tile size (mult of 4)
#define LPAD (4 * TS)                    // list pad region (offs read to +3*TS)
#define PADOFF (NH * 2048)               // byte offset of zeroed row 512 of wT

__device__ constexpr float KV = (float)(0.001 * 100.0);            // DT*TAU_MEM_INV
__device__ constexpr float KI = (float)(0.001 * 200.0);            // DT*TAU_SYN_INV
__device__ constexpr float KB = (float)(0.001 * (1.0 / 800.0));    // DT*TAU_ADAPT_INV
__device__ constexpr float KJ = (float)((1.0 / 800.0) * 1.8);      // TAU_ADAPT_INV*BETA

// ---------------- transpose w_rec (512x512): wT[j][n] = w_rec[n][j] ----------
__global__ void transp512(const float* __restrict__ in, float* __restrict__ ot) {
    __shared__ float tile[32][33];
    const int tx = threadIdx.x;            // 0..31
    const int ty = threadIdx.y;            // 0..7
    const int jcol = blockIdx.x * 32 + tx;
    const int row0 = blockIdx.y * 32;
    for (int r = ty; r < 32; r += 8)
        tile[r][tx] = in[(size_t)(row0 + r) * NH + jcol];
    __syncthreads();
    const int ncol = blockIdx.y * 32 + tx;
    const int jrow0 = blockIdx.x * 32;
    for (int r = ty; r < 32; r += 8)
        ot[(size_t)(jrow0 + r) * NH + ncol] = tile[tx][r];
}

// zero row 512 of wT (padding target for unconditional gather tiles)
__global__ void zrow(float* __restrict__ wT) {
    wT[(size_t)NH * NH + threadIdx.x] = 0.0f;
}

// ---------------- fp32 GEMM: F[m][n] = sum_k X[m][k] * W[n][k] ---------------
// UNCHANGED from round 2 (bitwise-verified against the np reference).
__global__ __launch_bounds__(256)
void gemm_ff(const float* __restrict__ X, const float* __restrict__ W,
             float* __restrict__ F, int M) {
    const int bx = blockIdx.x;   // n-tile: 0..3
    const int by = blockIdx.y;   // m-tile
    const int tid = threadIdx.x;

    __shared__ float As[32][128];
    __shared__ float Bs[32][128];

    const int tn0 = (tid & 15) * 8;
    const int tm0 = (tid >> 4) * 8;
    float acc[8][8] = {};

    const int am = tid >> 1;
    const int aq = (tid & 1) * 4;

    const float* Xb = X + (size_t)(by * 128 + am) * NIN;
    const float* Wb = W + (size_t)(bx * 128 + am) * NIN;

    for (int k0 = 0; k0 < NIN; k0 += 32) {
        __syncthreads();
#pragma unroll
        for (int i2 = 0; i2 < 4; ++i2) {
            const int q = aq + i2;
            float4 xa = *reinterpret_cast<const float4*>(Xb + k0 + q * 4);
            As[q * 4 + 0][am] = xa.x; As[q * 4 + 1][am] = xa.y;
            As[q * 4 + 2][am] = xa.z; As[q * 4 + 3][am] = xa.w;
            float4 wa = *reinterpret_cast<const float4*>(Wb + k0 + q * 4);
            Bs[q * 4 + 0][am] = wa.x; Bs[q * 4 + 1][am] = wa.y;
            Bs[q * 4 + 2][am] = wa.z; Bs[q * 4 + 3][am] = wa.w;
        }
        __syncthreads();
#pragma unroll 8
        for (int kk = 0; kk < 32; ++kk) {
            float4 a0 = *reinterpret_cast<const float4*>(&As[kk][tm0]);
            float4 a1 = *reinterpret_cast<const float4*>(&As[kk][tm0 + 4]);
            float4 b0 = *reinterpret_cast<const float4*>(&Bs[kk][tn0]);
            float4 b1 = *reinterpret_cast<const float4*>(&Bs[kk][tn0 + 4]);
            const float av[8] = {a0.x, a0.y, a0.z, a0.w, a1.x, a1.y, a1.z, a1.w};
            const float bv[8] = {b0.x, b0.y, b0.z, b0.w, b1.x, b1.y, b1.z, b1.w};
#pragma unroll
            for (int i = 0; i < 8; ++i)
#pragma unroll
                for (int j = 0; j < 8; ++j)
                    acc[i][j] += av[i] * bv[j];
        }
    }

    float* Fo = F + (size_t)(by * 128 + tm0) * NH + bx * 128 + tn0;
#pragma unroll
    for (int i = 0; i < 8; ++i) {
        *reinterpret_cast<float4*>(Fo + (size_t)i * NH) =
            make_float4(acc[i][0], acc[i][1], acc[i][2], acc[i][3]);
        *reinterpret_cast<float4*>(Fo + (size_t)i * NH + 4) =
            make_float4(acc[i][4], acc[i][5], acc[i][6], acc[i][7]);
    }
}

// ---------------- gather pipeline helpers ------------------------------------
// Offsets (block-uniform) read from LDS as int4 (ds_read_b128) one tile ahead
// of the data loads, so data-load addresses never wait lgkm in-tile. Data
// loads use uniform SGPR base + (row byte offset + column byte offset).
__device__ __forceinline__ void fill_offs(int4 (&o)[TS / 4], const int* lp,
                                          int base) {
#pragma unroll
    for (int i = 0; i < TS / 4; ++i)
        o[i] = *reinterpret_cast<const int4*>(lp + base + 4 * i);
}

__device__ __forceinline__ void fill_data(float (&buf)[TS], const int4 (&o)[TS / 4],
                                          const char* wb, unsigned n4) {
#pragma unroll
    for (int i = 0; i < TS / 4; ++i) {
        buf[4 * i + 0] = *reinterpret_cast<const float*>(wb + (unsigned)(o[i].x + (int)n4));
        buf[4 * i + 1] = *reinterpret_cast<const float*>(wb + (unsigned)(o[i].y + (int)n4));
        buf[4 * i + 2] = *reinterpret_cast<const float*>(wb + (unsigned)(o[i].z + (int)n4));
        buf[4 * i + 3] = *reinterpret_cast<const float*>(wb + (unsigned)(o[i].w + (int)n4));
    }
}

__device__ __forceinline__ void add_tile(const float (&buf)[TS], float& rec) {
#pragma unroll
    for (int i = 0; i < TS; ++i) rec = __fadd_rn(rec, buf[i]);
}

// ---------------- scan kernel: one WG (512 thr) per batch element -----------
// st layout: [z | v | i | b], each BB*NH floats.
__global__ __launch_bounds__(512, 1)
void lsnn_scan(const float* __restrict__ F, const float* __restrict__ wT,
               const float* __restrict__ z0, const float* __restrict__ v0,
               const float* __restrict__ i0, const float* __restrict__ b0,
               float* __restrict__ out, float* __restrict__ st,
               int t0, int Tc, int first, int last) {
    const int n    = threadIdx.x;        // neuron / column 0..511
    const int b    = blockIdx.x;         // batch
    const int lane = n & 63;
    const int wv   = n >> 6;             // wave 0..7
    const size_t bn = (size_t)b * NH + n;

    __shared__ __align__(16) int lists[2][NH + LPAD];  // row byte offsets + pad
    __shared__ int cnts[2][8];

    float v, cur, bb, zprev;
    if (first) {
        zprev = z0[bn]; v = v0[bn]; cur = i0[bn]; bb = b0[bn];
    } else {
        zprev = st[0 * BB * NH + bn];
        v     = st[1 * BB * NH + bn];
        cur   = st[2 * BB * NH + bn];
        bb    = st[3 * BB * NH + bn];
    }

    // ---- initial list build (buffer 0), ascending neuron order -------------
    int cnt;
    {
        const unsigned long long m = __ballot(zprev > 0.0f);
        if (lane == 0) cnts[0][wv] = __popcll(m);
        __syncthreads();
        int base = 0, tot = 0;
        for (int q = 0; q < 8; ++q) {
            const int c = cnts[0][q];
            if (q < wv) base += c;
            tot += c;
        }
        if (zprev > 0.0f)
            lists[0][base + __popcll(m & ((1ull << lane) - 1ull))] = n << 11;
        if (n < LPAD) lists[0][tot + n] = PADOFF;   // pad region
        __syncthreads();
        cnt = tot;
    }
    int par = 0;

    const char*  wb = reinterpret_cast<const char*>(wT);   // uniform base (SGPR)
    const unsigned n4 = (unsigned)n * 4u;                  // column byte offset
    const float* Fp = F + (size_t)b * NH + n;
    float* op = out + ((size_t)t0 * BB + b) * NH + n;

    for (int t = 0; t < Tc; ++t) {
        const int* lp = lists[par];
        float bA[TS], bB[TS];
        int4  oA[TS / 4], oB[TS / 4];

        // ---- t.0: offset prefetch for tiles 0/1; lgkm latency hides under
        //           the elementwise update below ------------------------------
        fill_offs(oA, lp, 0);
        fill_offs(oB, lp, TS);
        __builtin_amdgcn_sched_barrier(0);

        // ---- t.1: prefetch F, elementwise update, ballot --------------------
        const float fval = Fp[(size_t)t * BB * NH];   // consumed after gather
        const float v_dec = __fadd_rn(v, __fmul_rn(KV, __fadd_rn(__fsub_rn(0.0f, v), cur)));
        const float i_dec = __fsub_rn(cur, __fmul_rn(KI, cur));
        const float b_dec = __fadd_rn(bb, __fmul_rn(KB, __fsub_rn(1.0f, bb)));
        const float zn = (__fsub_rn(v_dec, b_dec) > 0.0f) ? 1.0f : 0.0f;
        v  = (zn > 0.0f) ? 0.0f : v_dec;
        bb = __fadd_rn(b_dec, __fmul_rn(zn, KJ));
        op[0] = zn;
        op += (size_t)BB * NH;
        const unsigned long long mm = __ballot(zn > 0.0f);
        if (lane == 0) cnts[par ^ 1][wv] = __popcll(mm);

        // ---- t.2: pipelined serial gather over lists[par] -------------------
        // One ascending __fadd_rn chain per column (bitwise == BLAS).
        // Data loads issue immediately from pre-read offsets (no in-tile
        // lgkm); sched_barrier after each data group pins the 16 loads ahead
        // of the previous tile's add chain (auto-waitcnt vmcnt(16), not 0).
        // Next tile's offset ds_reads interleave into the add chain.
        float rec = 0.0f;
        if (cnt > 0) {
            fill_data(bA, oA, wb, n4);            // data(0) in flight
            __builtin_amdgcn_sched_barrier(0);
            fill_offs(oA, lp, 2 * TS);            // offs(2)
            int kt = 0;
            for (;;) {
                fill_data(bB, oB, wb, n4);        // data(t+1)
                __builtin_amdgcn_sched_barrier(0);
                fill_offs(oB, lp, kt + 3 * TS);   // offs(t+3)
                add_tile(bA, rec);                // chain tile t
                kt += TS; if (kt >= cnt) break;
                fill_data(bA, oA, wb, n4);
                __builtin_amdgcn_sched_barrier(0);
                fill_offs(oA, lp, kt + 3 * TS);
                add_tile(bB, rec);
                kt += TS; if (kt >= cnt) break;
            }
        }
        cur = __fadd_rn(__fadd_rn(i_dec, fval), rec);
        zprev = zn;

        __syncthreads();   // B1: cnts[par^1] published; lists[par] drained

        // ---- t.3: build next list (lists[par^1]) ----------------------------
        int base = 0, tot = 0;
        for (int q = 0; q < 8; ++q) {
            const int c = cnts[par ^ 1][q];
            if (q < wv) base += c;
            tot += c;
        }
        if (zn > 0.0f)
            lists[par ^ 1][base + __popcll(mm & ((1ull << lane) - 1ull))] = n << 11;
        if (n < LPAD) lists[par ^ 1][tot + n] = PADOFF;
        __syncthreads();   // B2: lists[par^1] ready

        par ^= 1;
        cnt = tot;
    }

    st[0 * BB * NH + bn] = zprev;
    st[1 * BB * NH + bn] = v;
    st[2 * BB * NH + bn] = cur;
    st[3 * BB * NH + bn] = bb;
    if (last) {
        float* tail = out + (size_t)TT * BB * NH;
        tail[0 * BB * NH + bn] = zprev;  // zT
        tail[1 * BB * NH + bn] = v;      // vT
        tail[2 * BB * NH + bn] = cur;    // iT
        tail[3 * BB * NH + bn] = bb;     // bT
    }
}

// ---------------------------------------------------------------------------
extern "C" void kernel_launch(void* const* d_in, const int* in_sizes, int n_in,
                              void* d_out, int out_size, void* d_ws, size_t ws_size,
                              hipStream_t stream) {
    const float* X     = (const float*)d_in[0];
    const float* z0    = (const float*)d_in[1];
    const float* v0    = (const float*)d_in[2];
    const float* i0    = (const float*)d_in[3];
    const float* b0    = (const float*)d_in[4];
    const float* w_in  = (const float*)d_in[5];
    const float* w_rec = (const float*)d_in[6];
    float* out = (float*)d_out;

    char* ws = (char*)d_ws;
    float* wT = (float*)ws;                                    // 1 MB + zero row
    const size_t wT_bytes = ((size_t)NH * NH + NH) * 4 + 2048;
    float* st = (float*)(ws + wT_bytes);                       // 512 KB
    char*  fbase = ws + wT_bytes + (512u << 10);

    const long long per = (long long)BB * NH * 4;              // bytes/step of F
    long long avail = (long long)ws_size - (long long)(wT_bytes + (512u << 10));
    int Tc;
    if (avail >= 2 * per * TT) {
        Tc = TT;
    } else {
        Tc = (int)(avail / (2 * per));
        if (Tc > TT) Tc = TT;
        Tc &= ~1;
        if (Tc < 2) Tc = 2;
    }
    const size_t fbytes = (size_t)Tc * per;
    float* Fb[2] = { (float*)fbase, (float*)(fbase + fbytes) };

    transp512<<<dim3(16, 16), dim3(32, 8), 0, stream>>>(w_rec, wT);
    zrow<<<1, NH, 0, stream>>>(wT);

    int t0 = 0, buf = 0;
    bool firstc = true;
    while (t0 < TT) {
        const int Tcur = (Tc < TT - t0) ? Tc : (TT - t0);
        const int Mc = Tcur * BB;
        gemm_ff<<<dim3(4, Mc / 128), 256, 0, stream>>>(
            X + (size_t)t0 * BB * NIN, w_in, Fb[buf], Mc);
        lsnn_scan<<<dim3(BB), dim3(512), 0, stream>>>(
            Fb[buf], wT, z0, v0, i0, b0, out, st,
            t0, Tcur, firstc ? 1 : 0, (t0 + Tcur >= TT) ? 1 : 0);
        firstc = false;
        buf ^= 1;
        t0 += Tcur;
    }
}